// Round 1
// baseline (5024.150 us; speedup 1.0000x reference)
//
#include <hip/hip_runtime.h>
#include <math.h>

#define NVOX 65536
#define DM 256
#define NH 8
#define HDIM 32
#define DFFN 2048
#define SSZ 128
#define SNUM 512

// ============================= gather =============================
// qk[j] = src[inds[j]] + pos[inds[j]];  feat[j] = src[inds[j]]
__global__ __launch_bounds__(256)
void gather_kernel(const float* __restrict__ src, const float* __restrict__ pos,
                   const int* __restrict__ inds,
                   float* __restrict__ qk, float* __restrict__ feat) {
    int j = blockIdx.x * 4 + (threadIdx.x >> 6);
    int lane = threadIdx.x & 63;
    int v = inds[j];
    float4 a = ((const float4*)(src + (size_t)v * DM))[lane];
    float4 p = ((const float4*)(pos + (size_t)v * DM))[lane];
    ((float4*)(qk  + (size_t)j * DM))[lane] =
        make_float4(a.x + p.x, a.y + p.y, a.z + p.z, a.w + p.w);
    ((float4*)(feat + (size_t)j * DM))[lane] = a;
}

// ============================= GEMM ===============================
// C[M,N] = A[M,K] @ W[N,K]^T + bias[N], optional ReLU.
// BM=128, BN=64, BK=16; 256 threads; each thread 8x4 outputs.
#define BM 128
#define BN 64
#define BK 16

template<bool RELU>
__global__ __launch_bounds__(256)
void gemm_bt(const float* __restrict__ A, const float* __restrict__ W,
             const float* __restrict__ bias, float* __restrict__ C,
             int M, int N, int K) {
    __shared__ float As[BK][BM + 4];
    __shared__ float Ws[BK][BN + 4];
    int tid = threadIdx.x;
    int tx = tid & 15;          // n direction (x4)
    int ty = tid >> 4;          // m direction (x8)
    int mBase = blockIdx.x * BM;
    int nBase = blockIdx.y * BN;

    float acc[8][4];
#pragma unroll
    for (int i = 0; i < 8; i++)
#pragma unroll
        for (int j = 0; j < 4; j++) acc[i][j] = 0.f;

    for (int k0 = 0; k0 < K; k0 += BK) {
        // stage A tile (128 rows x 16 k), transposed into As[k][m]
#pragma unroll
        for (int u = 0; u < 2; u++) {
            int idx = tid + u * 256;
            int row = idx >> 2;
            int kk = (idx & 3) << 2;
            float4 v = *(const float4*)(A + (size_t)(mBase + row) * K + k0 + kk);
            As[kk + 0][row] = v.x; As[kk + 1][row] = v.y;
            As[kk + 2][row] = v.z; As[kk + 3][row] = v.w;
        }
        // stage W tile (64 rows x 16 k)
        {
            int row = tid >> 2;
            int kk = (tid & 3) << 2;
            float4 v = *(const float4*)(W + (size_t)(nBase + row) * K + k0 + kk);
            Ws[kk + 0][row] = v.x; Ws[kk + 1][row] = v.y;
            Ws[kk + 2][row] = v.z; Ws[kk + 3][row] = v.w;
        }
        __syncthreads();
#pragma unroll
        for (int kk = 0; kk < BK; kk++) {
            float4 w4 = *(const float4*)&Ws[kk][tx << 2];
            float4 a0 = *(const float4*)&As[kk][ty << 3];
            float4 a1 = *(const float4*)&As[kk][(ty << 3) + 4];
            float am[8] = {a0.x, a0.y, a0.z, a0.w, a1.x, a1.y, a1.z, a1.w};
            float wn[4] = {w4.x, w4.y, w4.z, w4.w};
#pragma unroll
            for (int i = 0; i < 8; i++)
#pragma unroll
                for (int j = 0; j < 4; j++)
                    acc[i][j] = fmaf(am[i], wn[j], acc[i][j]);
        }
        __syncthreads();
    }

    float4 b4 = *(const float4*)(bias + nBase + (tx << 2));
    float bn[4] = {b4.x, b4.y, b4.z, b4.w};
#pragma unroll
    for (int i = 0; i < 8; i++) {
        int row = mBase + (ty << 3) + i;
        float4 o;
        o.x = acc[i][0] + bn[0];
        o.y = acc[i][1] + bn[1];
        o.z = acc[i][2] + bn[2];
        o.w = acc[i][3] + bn[3];
        if (RELU) {
            o.x = fmaxf(o.x, 0.f); o.y = fmaxf(o.y, 0.f);
            o.z = fmaxf(o.z, 0.f); o.w = fmaxf(o.w, 0.f);
        }
        *(float4*)(C + (size_t)row * N + nBase + (tx << 2)) = o;
    }
}

// ============================ attention ===========================
// One block per (set, head). 128 threads; thread t owns query row t.
// QK buffer: (NVOX, 512): cols [0,256)=Q, [256,512)=K (col = h*32+d).
__global__ __launch_bounds__(128)
void attn_kernel(const float* __restrict__ QK, const float* __restrict__ V,
                 const unsigned char* __restrict__ mask,
                 float* __restrict__ ao) {
    int s = blockIdx.x;
    int h = blockIdx.y;
    int t = threadIdx.x;
    __shared__ float Ks[SSZ][HDIM + 4];
    __shared__ float Vs[SSZ][HDIM + 4];
    __shared__ unsigned char msk[SSZ];

    size_t row = (size_t)(s * SSZ + t);
    const float4* kp = (const float4*)(QK + row * 512 + 256 + h * HDIM);
    const float4* vp = (const float4*)(V + row * 256 + h * HDIM);
#pragma unroll
    for (int u = 0; u < 8; u++) {
        *(float4*)&Ks[t][u * 4] = kp[u];
        *(float4*)&Vs[t][u * 4] = vp[u];
    }
    float q[HDIM];
    const float4* qp = (const float4*)(QK + row * 512 + h * HDIM);
#pragma unroll
    for (int u = 0; u < 8; u++) {
        float4 x = qp[u];
        q[u * 4 + 0] = x.x; q[u * 4 + 1] = x.y;
        q[u * 4 + 2] = x.z; q[u * 4 + 3] = x.w;
    }
    msk[t] = mask[s * SSZ + t];
    __syncthreads();

    const float SCALE = 0.17677669529663687f;  // 1/sqrt(32)
    float m = -1e30f, l = 0.f;
    float acc[HDIM];
#pragma unroll
    for (int d = 0; d < HDIM; d++) acc[d] = 0.f;

    for (int k = 0; k < SSZ; k++) {
        if (msk[k]) continue;   // exp(-1e9 - m) underflows to 0 in fp32
        float sdot = 0.f;
#pragma unroll
        for (int u = 0; u < 8; u++) {
            float4 kk4 = *(const float4*)&Ks[k][u * 4];
            sdot = fmaf(q[u * 4 + 0], kk4.x, sdot);
            sdot = fmaf(q[u * 4 + 1], kk4.y, sdot);
            sdot = fmaf(q[u * 4 + 2], kk4.z, sdot);
            sdot = fmaf(q[u * 4 + 3], kk4.w, sdot);
        }
        float sc = sdot * SCALE;
        float nm = fmaxf(m, sc);
        float c = __expf(m - nm);
        float p = __expf(sc - nm);
        l = fmaf(l, c, p);
        m = nm;
#pragma unroll
        for (int u = 0; u < 8; u++) {
            float4 vv4 = *(const float4*)&Vs[k][u * 4];
            acc[u * 4 + 0] = fmaf(acc[u * 4 + 0], c, p * vv4.x);
            acc[u * 4 + 1] = fmaf(acc[u * 4 + 1], c, p * vv4.y);
            acc[u * 4 + 2] = fmaf(acc[u * 4 + 2], c, p * vv4.z);
            acc[u * 4 + 3] = fmaf(acc[u * 4 + 3], c, p * vv4.w);
        }
    }
    float inv = 1.f / l;
    float* op = ao + row * 256 + h * HDIM;
#pragma unroll
    for (int u = 0; u < 8; u++) {
        float4 o;
        o.x = acc[u * 4 + 0] * inv; o.y = acc[u * 4 + 1] * inv;
        o.z = acc[u * 4 + 2] * inv; o.w = acc[u * 4 + 3] * inv;
        *(float4*)(op + u * 4) = o;
    }
}

// ======================== LayerNorm helpers =======================
__device__ inline float4 ln4(float4 t, int lane, const float* __restrict__ g,
                             const float* __restrict__ b) {
    float s = t.x + t.y + t.z + t.w;
    float s2 = t.x * t.x + t.y * t.y + t.z * t.z + t.w * t.w;
#pragma unroll
    for (int off = 32; off; off >>= 1) {
        s += __shfl_xor(s, off);
        s2 += __shfl_xor(s2, off);
    }
    float mean = s * (1.0f / 256.0f);
    float var = fmaf(-mean, mean, s2 * (1.0f / 256.0f));
    float rs = rsqrtf(var + 1e-5f);
    float4 g4 = ((const float4*)g)[lane];
    float4 b4 = ((const float4*)b)[lane];
    float4 o;
    o.x = fmaf((t.x - mean) * rs, g4.x, b4.x);
    o.y = fmaf((t.y - mean) * rs, g4.y, b4.y);
    o.z = fmaf((t.z - mean) * rs, g4.z, b4.z);
    o.w = fmaf((t.w - mean) * rs, g4.w, b4.w);
    return o;
}

// x[inds[j]] = LN(prev[inds[j]] + a[j])   (inverse-permutation scatter)
__global__ __launch_bounds__(256)
void scatter_ln_kernel(const float* __restrict__ a, const int* __restrict__ inds,
                       const float* __restrict__ prev,
                       const float* __restrict__ g, const float* __restrict__ b,
                       float* __restrict__ x) {
    int j = blockIdx.x * 4 + (threadIdx.x >> 6);
    int lane = threadIdx.x & 63;
    int v = inds[j];
    float4 av = ((const float4*)(a + (size_t)j * DM))[lane];
    float4 pv = ((const float4*)(prev + (size_t)v * DM))[lane];
    float4 t = make_float4(av.x + pv.x, av.y + pv.y, av.z + pv.z, av.w + pv.w);
    float4 o = ln4(t, lane, g, b);
    ((float4*)(x + (size_t)v * DM))[lane] = o;
}

// out[v] = LN( LN(x[v]+y[v], g2,b2) + prev[v], gl,bl )
__global__ __launch_bounds__(256)
void final_ln_kernel(const float* __restrict__ x, const float* __restrict__ y,
                     const float* __restrict__ prev,
                     const float* __restrict__ g2, const float* __restrict__ b2,
                     const float* __restrict__ gl, const float* __restrict__ bl,
                     float* __restrict__ out) {
    int v = blockIdx.x * 4 + (threadIdx.x >> 6);
    int lane = threadIdx.x & 63;
    size_t base = (size_t)v * DM;
    float4 xv = ((const float4*)(x + base))[lane];
    float4 yv = ((const float4*)(y + base))[lane];
    float4 t = make_float4(xv.x + yv.x, xv.y + yv.y, xv.z + yv.z, xv.w + yv.w);
    float4 t2 = ln4(t, lane, g2, b2);
    float4 pv = ((const float4*)(prev + base))[lane];
    float4 u = make_float4(t2.x + pv.x, t2.y + pv.y, t2.z + pv.z, t2.w + pv.w);
    float4 o = ln4(u, lane, gl, bl);
    ((float4*)(out + base))[lane] = o;
}

// ============================= launch =============================
extern "C" void kernel_launch(void* const* d_in, const int* in_sizes, int n_in,
                              void* d_out, int out_size, void* d_ws, size_t ws_size,
                              hipStream_t stream) {
    const float* src       = (const float*)d_in[0];
    const float* pos_embed = (const float*)d_in[1];
    const int*   inds_all  = (const int*)d_in[2];
    const unsigned char* masks_all = (const unsigned char*)d_in[3];
    const float* w_qkv = (const float*)d_in[4];
    const float* b_qkv = (const float*)d_in[5];
    const float* w_out = (const float*)d_in[6];
    const float* b_out = (const float*)d_in[7];
    const float* w_ff1 = (const float*)d_in[8];
    const float* b_ff1 = (const float*)d_in[9];
    const float* w_ff2 = (const float*)d_in[10];
    const float* b_ff2 = (const float*)d_in[11];
    const float* g_n1 = (const float*)d_in[12];
    const float* b_n1 = (const float*)d_in[13];
    const float* g_n2 = (const float*)d_in[14];
    const float* b_n2 = (const float*)d_in[15];
    const float* g_ln = (const float*)d_in[16];
    const float* b_ln = (const float*)d_in[17];
    float* out = (float*)d_out;

    const size_t NVF = (size_t)NVOX * DM;  // 16,777,216 floats
    float* ws   = (float*)d_ws;
    float* qk   = ws;             // later reused as attention output (ao)
    float* feat = ws + NVF;       // later reused as post-Wo activations (a)
    float* QKb  = ws + 2 * NVF;   // 2*NVF; first half later reused as x
    float* Vb   = ws + 4 * NVF;   // later reused as FFN output (y)
    float* h    = ws + 5 * NVF;   // FFN hidden chunk

    // adaptive FFN row-chunk so h fits in remaining ws
    long long hav = (long long)(ws_size / sizeof(float)) - 5LL * (long long)NVF;
    long long c = hav / DFFN;
    if (c > NVOX) c = NVOX;
    c &= ~127LL;
    int chunk = (c < 128) ? 128 : (int)c;

    for (int i = 0; i < 2; i++) {
        const float* prev = (i == 0) ? src : out;  // identity / layer input
        float* out_cur = out;                       // layer0 -> d_out (reused), layer1 -> d_out
        const int* inds = inds_all + (size_t)i * 2 * SNUM * SSZ;
        const unsigned char* mask = masks_all + (size_t)i * 2 * SNUM * SSZ;
        const float* pos  = pos_embed + (size_t)i * NVF;
        const float* wqkv = w_qkv + (size_t)i * 3 * DM * DM;
        const float* bqkv = b_qkv + (size_t)i * 3 * DM;
        const float* wo   = w_out + (size_t)i * DM * DM;
        const float* bo   = b_out + (size_t)i * DM;
        const float* wff1 = w_ff1 + (size_t)i * DFFN * DM;
        const float* bff1 = b_ff1 + (size_t)i * DFFN;
        const float* wff2 = w_ff2 + (size_t)i * DM * DFFN;
        const float* bff2 = b_ff2 + (size_t)i * DM;

        gather_kernel<<<NVOX / 4, 256, 0, stream>>>(prev, pos, inds, qk, feat);

        // [Q|K] = qk @ [Wq;Wk]^T   (N=512, K=256)
        gemm_bt<false><<<dim3(NVOX / BM, 512 / BN), 256, 0, stream>>>(
            qk, wqkv, bqkv, QKb, NVOX, 512, DM);
        // V = feat @ Wv^T
        gemm_bt<false><<<dim3(NVOX / BM, DM / BN), 256, 0, stream>>>(
            feat, wqkv + 512 * DM, bqkv + 512, Vb, NVOX, DM, DM);

        // attention -> ao (reuse qk buffer)
        attn_kernel<<<dim3(SNUM, NH), 128, 0, stream>>>(QKb, Vb, mask, qk);

        // a = ao @ Wo^T + bo (reuse feat buffer)
        gemm_bt<false><<<dim3(NVOX / BM, DM / BN), 256, 0, stream>>>(
            qk, wo, bo, feat, NVOX, DM, DM);

        // x[v] = LN(prev[v] + a[j])  (x reuses first half of QKb)
        float* x = QKb;
        scatter_ln_kernel<<<NVOX / 4, 256, 0, stream>>>(
            feat, inds, prev, g_n1 + i * DM, b_n1 + i * DM, x);

        // FFN (row-chunked): y = relu(x@W1^T+b1)@W2^T+b2  (y reuses Vb)
        float* y = Vb;
        for (int r0 = 0; r0 < NVOX; r0 += chunk) {
            int rows = (NVOX - r0 < chunk) ? (NVOX - r0) : chunk;
            gemm_bt<true><<<dim3(rows / BM, DFFN / BN), 256, 0, stream>>>(
                x + (size_t)r0 * DM, wff1, bff1, h, rows, DFFN, DM);
            gemm_bt<false><<<dim3(rows / BM, DM / BN), 256, 0, stream>>>(
                h, wff2, bff2, y + (size_t)r0 * DM, rows, DM, DFFN);
        }

        // out = LN( LN(x+y) + prev )
        final_ln_kernel<<<NVOX / 4, 256, 0, stream>>>(
            x, y, prev, g_n2 + i * DM, b_n2 + i * DM,
            g_ln + i * DM, b_ln + i * DM, out_cur);
    }
}

// Round 2
// 1751.748 us; speedup vs baseline: 2.8681x; 2.8681x over previous
//
#include <hip/hip_runtime.h>
#include <math.h>

#define NVOX 65536
#define DM 256
#define NH 8
#define HDIM 32
#define DFFN 2048
#define SSZ 128
#define SNUM 512

#define AS1 __attribute__((address_space(1)))
#define AS3 __attribute__((address_space(3)))

typedef __attribute__((ext_vector_type(8))) __bf16 bf16x8;
typedef __attribute__((ext_vector_type(4))) float f32x4;

__device__ __forceinline__ unsigned short f2bf(float f) {
    unsigned int u = __float_as_uint(f);
    u += 0x7fffu + ((u >> 16) & 1u);
    return (unsigned short)(u >> 16);
}

// ===================== weight fp32 -> bf16 ========================
__global__ __launch_bounds__(256)
void cvt_bf16_kernel(const float* __restrict__ in, unsigned short* __restrict__ out, int n) {
    int i = blockIdx.x * 256 + threadIdx.x;
    int stride = gridDim.x * 256;
    for (; i < n; i += stride) out[i] = f2bf(in[i]);
}

// ============================= gather =============================
// qk_bf[j] = bf16(src[inds[j]] + pos[inds[j]]);  feat_bf[j] = bf16(src[inds[j]])
__global__ __launch_bounds__(256)
void gather_kernel(const float* __restrict__ src, const float* __restrict__ pos,
                   const int* __restrict__ inds,
                   unsigned short* __restrict__ qk, unsigned short* __restrict__ feat) {
    int j = blockIdx.x * 4 + (threadIdx.x >> 6);
    int lane = threadIdx.x & 63;
    int v = inds[j];
    float4 a = ((const float4*)(src + (size_t)v * DM))[lane];
    float4 p = ((const float4*)(pos + (size_t)v * DM))[lane];
    ushort4 qo, fo;
    qo.x = f2bf(a.x + p.x); qo.y = f2bf(a.y + p.y);
    qo.z = f2bf(a.z + p.z); qo.w = f2bf(a.w + p.w);
    fo.x = f2bf(a.x); fo.y = f2bf(a.y); fo.z = f2bf(a.z); fo.w = f2bf(a.w);
    ((ushort4*)(qk   + (size_t)j * DM))[lane] = qo;
    ((ushort4*)(feat + (size_t)j * DM))[lane] = fo;
}

// ========================= bf16 MFMA GEMM =========================
// C[M,N] = A[M,K](bf16) @ W[N,K](bf16)^T + bias[N](f32); opt ReLU; out f32 or bf16.
// m97 structure: 128x128 tile, BK=32, 4 waves (2x2), 16x16x32 MFMA,
// global_load_lds width 16, linear LDS, 2 barriers per K-step.
template<bool RELU, bool OBF16>
__global__ __launch_bounds__(256)
void gemm_mfma(const unsigned short* __restrict__ A, const unsigned short* __restrict__ W,
               const float* __restrict__ bias, void* __restrict__ Cout,
               int M, int N, int K) {
    __shared__ alignas(16) unsigned short As[128 * 32];
    __shared__ alignas(16) unsigned short Bs[128 * 32];
    int tid = threadIdx.x;
    int wave = tid >> 6, lane = tid & 63;
    int waveM = wave >> 1, waveN = wave & 1;
    int mBase = blockIdx.x * 128, nBase = blockIdx.y * 128;

    f32x4 acc[4][4];
    const f32x4 zero = {0.f, 0.f, 0.f, 0.f};
#pragma unroll
    for (int i = 0; i < 4; i++)
#pragma unroll
        for (int j = 0; j < 4; j++) acc[i][j] = zero;

    int lrow = lane >> 2;        // 0..15 row within 16-row stripe
    int lk   = (lane & 3) * 8;   // element offset within BK (16B per lane)
    int kh   = (lane >> 4) * 8;  // fragment k-offset
    int rr   = lane & 15;        // fragment row/col

    for (int k0 = 0; k0 < K; k0 += 32) {
        if (k0) __syncthreads();
#pragma unroll
        for (int u = 0; u < 2; u++) {
            int w2 = wave * 2 + u;  // stripe index 0..7 (16 rows each)
            const unsigned short* ga = A + (size_t)(mBase + w2 * 16 + lrow) * K + k0 + lk;
            __builtin_amdgcn_global_load_lds((const AS1 void*)ga, (AS3 void*)(As + w2 * 512), 16, 0, 0);
            const unsigned short* gb = W + (size_t)(nBase + w2 * 16 + lrow) * K + k0 + lk;
            __builtin_amdgcn_global_load_lds((const AS1 void*)gb, (AS3 void*)(Bs + w2 * 512), 16, 0, 0);
        }
        __syncthreads();  // compiler drains vmcnt before barrier

        bf16x8 af[4], bfr[4];
#pragma unroll
        for (int i = 0; i < 4; i++)
            af[i] = *(const bf16x8*)(As + (waveM * 64 + i * 16 + rr) * 32 + kh);
#pragma unroll
        for (int j = 0; j < 4; j++)
            bfr[j] = *(const bf16x8*)(Bs + (waveN * 64 + j * 16 + rr) * 32 + kh);
#pragma unroll
        for (int i = 0; i < 4; i++)
#pragma unroll
            for (int j = 0; j < 4; j++)
                acc[i][j] = __builtin_amdgcn_mfma_f32_16x16x32_bf16(af[i], bfr[j], acc[i][j], 0, 0, 0);
    }

    // epilogue: C/D layout col=lane&15, row=(lane>>4)*4+reg  [m89-verified]
    int rbase = (lane >> 4) * 4;
#pragma unroll
    for (int j = 0; j < 4; j++) {
        int col = nBase + waveN * 64 + j * 16 + rr;
        float bj = bias[col];
#pragma unroll
        for (int i = 0; i < 4; i++) {
            int row0 = mBase + waveM * 64 + i * 16 + rbase;
#pragma unroll
            for (int r = 0; r < 4; r++) {
                float v = acc[i][j][r] + bj;
                if (RELU) v = fmaxf(v, 0.f);
                if (OBF16)
                    ((unsigned short*)Cout)[(size_t)(row0 + r) * N + col] = f2bf(v);
                else
                    ((float*)Cout)[(size_t)(row0 + r) * N + col] = v;
            }
        }
    }
}

// ============================ attention ===========================
// One block per (set, head). Thread t owns query row t. fp32 math, bf16 out.
__global__ __launch_bounds__(128)
void attn_kernel(const float* __restrict__ QK, const float* __restrict__ V,
                 const unsigned char* __restrict__ mask,
                 unsigned short* __restrict__ ao) {
    int s = blockIdx.x;
    int h = blockIdx.y;
    int t = threadIdx.x;
    __shared__ float Ks[SSZ][HDIM + 4];
    __shared__ float Vs[SSZ][HDIM + 4];
    __shared__ unsigned char msk[SSZ];

    size_t row = (size_t)(s * SSZ + t);
    const float4* kp = (const float4*)(QK + row * 512 + 256 + h * HDIM);
    const float4* vp = (const float4*)(V + row * 256 + h * HDIM);
#pragma unroll
    for (int u = 0; u < 8; u++) {
        *(float4*)&Ks[t][u * 4] = kp[u];
        *(float4*)&Vs[t][u * 4] = vp[u];
    }
    float q[HDIM];
    const float4* qp = (const float4*)(QK + row * 512 + h * HDIM);
#pragma unroll
    for (int u = 0; u < 8; u++) {
        float4 x = qp[u];
        q[u * 4 + 0] = x.x; q[u * 4 + 1] = x.y;
        q[u * 4 + 2] = x.z; q[u * 4 + 3] = x.w;
    }
    msk[t] = mask[s * SSZ + t];
    __syncthreads();

    const float SCALE = 0.17677669529663687f;  // 1/sqrt(32)
    float m = -1e30f, l = 0.f;
    float acc[HDIM];
#pragma unroll
    for (int d = 0; d < HDIM; d++) acc[d] = 0.f;

    for (int k = 0; k < SSZ; k++) {
        if (msk[k]) continue;   // exp(-1e9-m) underflows to 0 in fp32
        float sdot = 0.f;
#pragma unroll
        for (int u = 0; u < 8; u++) {
            float4 kk4 = *(const float4*)&Ks[k][u * 4];
            sdot = fmaf(q[u * 4 + 0], kk4.x, sdot);
            sdot = fmaf(q[u * 4 + 1], kk4.y, sdot);
            sdot = fmaf(q[u * 4 + 2], kk4.z, sdot);
            sdot = fmaf(q[u * 4 + 3], kk4.w, sdot);
        }
        float sc = sdot * SCALE;
        float nm = fmaxf(m, sc);
        float c = __expf(m - nm);
        float p = __expf(sc - nm);
        l = fmaf(l, c, p);
        m = nm;
#pragma unroll
        for (int u = 0; u < 8; u++) {
            float4 vv4 = *(const float4*)&Vs[k][u * 4];
            acc[u * 4 + 0] = fmaf(acc[u * 4 + 0], c, p * vv4.x);
            acc[u * 4 + 1] = fmaf(acc[u * 4 + 1], c, p * vv4.y);
            acc[u * 4 + 2] = fmaf(acc[u * 4 + 2], c, p * vv4.z);
            acc[u * 4 + 3] = fmaf(acc[u * 4 + 3], c, p * vv4.w);
        }
    }
    float inv = 1.f / l;
    unsigned short* op = ao + row * 256 + h * HDIM;
#pragma unroll
    for (int u = 0; u < 8; u++) {
        ushort4 o;
        o.x = f2bf(acc[u * 4 + 0] * inv);
        o.y = f2bf(acc[u * 4 + 1] * inv);
        o.z = f2bf(acc[u * 4 + 2] * inv);
        o.w = f2bf(acc[u * 4 + 3] * inv);
        ((ushort4*)op)[u] = o;
    }
}

// ======================== LayerNorm helpers =======================
__device__ inline float4 ln4(float4 t, int lane, const float* __restrict__ g,
                             const float* __restrict__ b) {
    float s = t.x + t.y + t.z + t.w;
    float s2 = t.x * t.x + t.y * t.y + t.z * t.z + t.w * t.w;
#pragma unroll
    for (int off = 32; off; off >>= 1) {
        s += __shfl_xor(s, off);
        s2 += __shfl_xor(s2, off);
    }
    float mean = s * (1.0f / 256.0f);
    float var = fmaf(-mean, mean, s2 * (1.0f / 256.0f));
    float rs = rsqrtf(var + 1e-5f);
    float4 g4 = ((const float4*)g)[lane];
    float4 b4 = ((const float4*)b)[lane];
    float4 o;
    o.x = fmaf((t.x - mean) * rs, g4.x, b4.x);
    o.y = fmaf((t.y - mean) * rs, g4.y, b4.y);
    o.z = fmaf((t.z - mean) * rs, g4.z, b4.z);
    o.w = fmaf((t.w - mean) * rs, g4.w, b4.w);
    return o;
}

// x[inds[j]] = LN(prev[inds[j]] + a[j]); dual write f32 + bf16
__global__ __launch_bounds__(256)
void scatter_ln_kernel(const float* __restrict__ a, const int* __restrict__ inds,
                       const float* __restrict__ prev,
                       const float* __restrict__ g, const float* __restrict__ b,
                       float* __restrict__ x, unsigned short* __restrict__ x_bf) {
    int j = blockIdx.x * 4 + (threadIdx.x >> 6);
    int lane = threadIdx.x & 63;
    int v = inds[j];
    float4 av = ((const float4*)(a + (size_t)j * DM))[lane];
    float4 pv = ((const float4*)(prev + (size_t)v * DM))[lane];
    float4 t = make_float4(av.x + pv.x, av.y + pv.y, av.z + pv.z, av.w + pv.w);
    float4 o = ln4(t, lane, g, b);
    ((float4*)(x + (size_t)v * DM))[lane] = o;
    ushort4 ob;
    ob.x = f2bf(o.x); ob.y = f2bf(o.y); ob.z = f2bf(o.z); ob.w = f2bf(o.w);
    ((ushort4*)(x_bf + (size_t)v * DM))[lane] = ob;
}

// out[v] = LN( LN(x[v]+y[v], g2,b2) + prev[v], gl,bl )
__global__ __launch_bounds__(256)
void final_ln_kernel(const float* __restrict__ x, const float* __restrict__ y,
                     const float* __restrict__ prev,
                     const float* __restrict__ g2, const float* __restrict__ b2,
                     const float* __restrict__ gl, const float* __restrict__ bl,
                     float* __restrict__ out) {
    int v = blockIdx.x * 4 + (threadIdx.x >> 6);
    int lane = threadIdx.x & 63;
    size_t base = (size_t)v * DM;
    float4 xv = ((const float4*)(x + base))[lane];
    float4 yv = ((const float4*)(y + base))[lane];
    float4 t = make_float4(xv.x + yv.x, xv.y + yv.y, xv.z + yv.z, xv.w + yv.w);
    float4 t2 = ln4(t, lane, g2, b2);
    float4 pv = ((const float4*)(prev + base))[lane];
    float4 u = make_float4(t2.x + pv.x, t2.y + pv.y, t2.z + pv.z, t2.w + pv.w);
    float4 o = ln4(u, lane, gl, bl);
    ((float4*)(out + base))[lane] = o;
}

// ============================= launch =============================
extern "C" void kernel_launch(void* const* d_in, const int* in_sizes, int n_in,
                              void* d_out, int out_size, void* d_ws, size_t ws_size,
                              hipStream_t stream) {
    const float* src       = (const float*)d_in[0];
    const float* pos_embed = (const float*)d_in[1];
    const int*   inds_all  = (const int*)d_in[2];
    const unsigned char* masks_all = (const unsigned char*)d_in[3];
    const float* w_qkv = (const float*)d_in[4];
    const float* b_qkv = (const float*)d_in[5];
    const float* w_out = (const float*)d_in[6];
    const float* b_out = (const float*)d_in[7];
    const float* w_ff1 = (const float*)d_in[8];
    const float* b_ff1 = (const float*)d_in[9];
    const float* w_ff2 = (const float*)d_in[10];
    const float* b_ff2 = (const float*)d_in[11];
    const float* g_n1 = (const float*)d_in[12];
    const float* b_n1 = (const float*)d_in[13];
    const float* g_n2 = (const float*)d_in[14];
    const float* b_n2 = (const float*)d_in[15];
    const float* g_ln = (const float*)d_in[16];
    const float* b_ln = (const float*)d_in[17];
    float* out = (float*)d_out;

    const size_t NVF = (size_t)NVOX * DM;  // 16,777,216
    // ws layout
    unsigned short* qk_bf   = (unsigned short*)d_ws;       // NVF bf16 (later: ao_bf)
    unsigned short* feat_bf = qk_bf + NVF;                 // NVF bf16 (later: x_bf)
    float* QKb = (float*)(feat_bf + NVF);                  // 2*NVF f32 (later: x | y)
    float* Vb  = QKb + 2 * NVF;                            // NVF f32 (later: a)
    unsigned short* wts = (unsigned short*)(Vb + NVF);
    const size_t SZ_QKV = (size_t)2 * 3 * DM * DM;   // 393216
    const size_t SZ_WO  = (size_t)2 * DM * DM;       // 131072
    const size_t SZ_FF1 = (size_t)2 * DFFN * DM;     // 1048576
    const size_t SZ_FF2 = (size_t)2 * DM * DFFN;     // 1048576
    unsigned short* wqkv_bf = wts;
    unsigned short* wo_bf   = wqkv_bf + SZ_QKV;
    unsigned short* wff1_bf = wo_bf + SZ_WO;
    unsigned short* wff2_bf = wff1_bf + SZ_FF1;
    unsigned short* hbuf    = wff2_bf + SZ_FF2;

    // FFN hidden chunk rows (bf16, DFFN wide) fitting in remaining ws
    size_t used_bytes = (char*)hbuf - (char*)d_ws;
    long long avail = (long long)ws_size - (long long)used_bytes;
    long long crows = avail / (DFFN * 2);
    if (crows > NVOX) crows = NVOX;
    crows &= ~127LL;
    int chunk = (crows < 128) ? 128 : (int)crows;

    // weights -> bf16 (both layers, once per call; deterministic)
    cvt_bf16_kernel<<<512, 256, 0, stream>>>(w_qkv, wqkv_bf, (int)SZ_QKV);
    cvt_bf16_kernel<<<256, 256, 0, stream>>>(w_out, wo_bf, (int)SZ_WO);
    cvt_bf16_kernel<<<1024, 256, 0, stream>>>(w_ff1, wff1_bf, (int)SZ_FF1);
    cvt_bf16_kernel<<<1024, 256, 0, stream>>>(w_ff2, wff2_bf, (int)SZ_FF2);

    for (int i = 0; i < 2; i++) {
        const float* prev = (i == 0) ? src : out;
        const int* inds = inds_all + (size_t)i * 2 * SNUM * SSZ;
        const unsigned char* mask = masks_all + (size_t)i * 2 * SNUM * SSZ;
        const float* pos  = pos_embed + (size_t)i * NVF;
        const unsigned short* wqkv = wqkv_bf + (size_t)i * 3 * DM * DM;
        const unsigned short* wo   = wo_bf + (size_t)i * DM * DM;
        const unsigned short* wff1 = wff1_bf + (size_t)i * DFFN * DM;
        const unsigned short* wff2 = wff2_bf + (size_t)i * DM * DFFN;
        const float* bqkv = b_qkv + (size_t)i * 3 * DM;
        const float* bo   = b_out + (size_t)i * DM;
        const float* bff1 = b_ff1 + (size_t)i * DFFN;
        const float* bff2 = b_ff2 + (size_t)i * DM;

        gather_kernel<<<NVOX / 4, 256, 0, stream>>>(prev, pos, inds, qk_bf, feat_bf);

        // [Q|K] = qk @ [Wq;Wk]^T  (N=512)
        gemm_mfma<false, false><<<dim3(NVOX / 128, 512 / 128), 256, 0, stream>>>(
            qk_bf, wqkv, bqkv, QKb, NVOX, 512, DM);
        // V = feat @ Wv^T
        gemm_mfma<false, false><<<dim3(NVOX / 128, DM / 128), 256, 0, stream>>>(
            feat_bf, wqkv + (size_t)512 * DM, bqkv + 512, Vb, NVOX, DM, DM);

        // attention -> ao (bf16, reuse qk_bf)
        attn_kernel<<<dim3(SNUM, NH), 128, 0, stream>>>(QKb, Vb, mask, qk_bf);

        // a = ao @ Wo^T + bo  (f32, reuse Vb)
        gemm_mfma<false, false><<<dim3(NVOX / 128, DM / 128), 256, 0, stream>>>(
            qk_bf, wo, bo, Vb, NVOX, DM, DM);

        // x = LN(prev + scatter(a))  -> f32 (QKb[0:NVF]) + bf16 (feat_bf)
        float* x = QKb;
        scatter_ln_kernel<<<NVOX / 4, 256, 0, stream>>>(
            Vb, inds, prev, g_n1 + i * DM, b_n1 + i * DM, x, feat_bf);

        // FFN row-chunked: h = relu(x@W1^T+b1) bf16; y = h@W2^T+b2 f32
        float* y = QKb + NVF;
        for (int r0 = 0; r0 < NVOX; r0 += chunk) {
            int rows = (NVOX - r0 < chunk) ? (NVOX - r0) : chunk;
            gemm_mfma<true, true><<<dim3(rows / 128, DFFN / 128), 256, 0, stream>>>(
                feat_bf + (size_t)r0 * DM, wff1, bff1, hbuf, rows, DFFN, DM);
            gemm_mfma<false, false><<<dim3(rows / 128, DM / 128), 256, 0, stream>>>(
                hbuf, wff2, bff2, y + (size_t)r0 * DM, rows, DM, DFFN);
        }

        // out = LN( LN(x+y) + prev )
        final_ln_kernel<<<NVOX / 4, 256, 0, stream>>>(
            x, y, prev, g_n2 + i * DM, b_n2 + i * DM,
            g_ln + i * DM, b_ln + i * DM, out);
    }
}

// Round 3
// 1211.133 us; speedup vs baseline: 4.1483x; 1.4464x over previous
//
#include <hip/hip_runtime.h>
#include <math.h>

#define NVOX 65536
#define DM 256
#define NH 8
#define HDIM 32
#define DFFN 2048
#define SSZ 128
#define SNUM 512

#define AS1 __attribute__((address_space(1)))
#define AS3 __attribute__((address_space(3)))

typedef __attribute__((ext_vector_type(8))) __bf16 bf16x8;
typedef __attribute__((ext_vector_type(8))) unsigned short u16x8;
typedef __attribute__((ext_vector_type(4))) float f32x4;

__device__ __forceinline__ unsigned short f2bf(float f) {
    unsigned int u = __float_as_uint(f);
    u += 0x7fffu + ((u >> 16) & 1u);
    return (unsigned short)(u >> 16);
}
__device__ __forceinline__ float bf2f(unsigned short u) {
    return __uint_as_float(((unsigned int)u) << 16);
}

// ===================== weight fp32 -> bf16 ========================
__global__ __launch_bounds__(256)
void cvt_bf16_kernel(const float* __restrict__ in, unsigned short* __restrict__ out, int n) {
    int i = blockIdx.x * 256 + threadIdx.x;
    int stride = gridDim.x * 256;
    for (; i < n; i += stride) out[i] = f2bf(in[i]);
}

// ============================= gather =============================
__global__ __launch_bounds__(256)
void gather_kernel(const float* __restrict__ src, const float* __restrict__ pos,
                   const int* __restrict__ inds,
                   unsigned short* __restrict__ qk, unsigned short* __restrict__ feat) {
    int j = blockIdx.x * 4 + (threadIdx.x >> 6);
    int lane = threadIdx.x & 63;
    int v = inds[j];
    float4 a = ((const float4*)(src + (size_t)v * DM))[lane];
    float4 p = ((const float4*)(pos + (size_t)v * DM))[lane];
    ushort4 qo, fo;
    qo.x = f2bf(a.x + p.x); qo.y = f2bf(a.y + p.y);
    qo.z = f2bf(a.z + p.z); qo.w = f2bf(a.w + p.w);
    fo.x = f2bf(a.x); fo.y = f2bf(a.y); fo.z = f2bf(a.z); fo.w = f2bf(a.w);
    ((ushort4*)(qk   + (size_t)j * DM))[lane] = qo;
    ((ushort4*)(feat + (size_t)j * DM))[lane] = fo;
}

// ========================= bf16 MFMA GEMM =========================
// C[M,N] = A[M,K](bf16) @ W[N,K](bf16)^T + bias[N](f32); opt ReLU; out f32 or bf16.
template<bool RELU, bool OBF16>
__global__ __launch_bounds__(256)
void gemm_mfma(const unsigned short* __restrict__ A, const unsigned short* __restrict__ W,
               const float* __restrict__ bias, void* __restrict__ Cout,
               int M, int N, int K) {
    __shared__ alignas(16) unsigned short As[128 * 32];
    __shared__ alignas(16) unsigned short Bs[128 * 32];
    int tid = threadIdx.x;
    int wave = tid >> 6, lane = tid & 63;
    int waveM = wave >> 1, waveN = wave & 1;
    int mBase = blockIdx.x * 128, nBase = blockIdx.y * 128;

    f32x4 acc[4][4];
    const f32x4 zero = {0.f, 0.f, 0.f, 0.f};
#pragma unroll
    for (int i = 0; i < 4; i++)
#pragma unroll
        for (int j = 0; j < 4; j++) acc[i][j] = zero;

    int lrow = lane >> 2;
    int lk   = (lane & 3) * 8;
    int kh   = (lane >> 4) * 8;
    int rr   = lane & 15;

    for (int k0 = 0; k0 < K; k0 += 32) {
        if (k0) __syncthreads();
#pragma unroll
        for (int u = 0; u < 2; u++) {
            int w2 = wave * 2 + u;
            const unsigned short* ga = A + (size_t)(mBase + w2 * 16 + lrow) * K + k0 + lk;
            __builtin_amdgcn_global_load_lds((const AS1 void*)ga, (AS3 void*)(As + w2 * 512), 16, 0, 0);
            const unsigned short* gb = W + (size_t)(nBase + w2 * 16 + lrow) * K + k0 + lk;
            __builtin_amdgcn_global_load_lds((const AS1 void*)gb, (AS3 void*)(Bs + w2 * 512), 16, 0, 0);
        }
        __syncthreads();

        bf16x8 af[4], bfr[4];
#pragma unroll
        for (int i = 0; i < 4; i++)
            af[i] = *(const bf16x8*)(As + (waveM * 64 + i * 16 + rr) * 32 + kh);
#pragma unroll
        for (int j = 0; j < 4; j++)
            bfr[j] = *(const bf16x8*)(Bs + (waveN * 64 + j * 16 + rr) * 32 + kh);
#pragma unroll
        for (int i = 0; i < 4; i++)
#pragma unroll
            for (int j = 0; j < 4; j++)
                acc[i][j] = __builtin_amdgcn_mfma_f32_16x16x32_bf16(af[i], bfr[j], acc[i][j], 0, 0, 0);
    }

    int rbase = (lane >> 4) * 4;
#pragma unroll
    for (int j = 0; j < 4; j++) {
        int col = nBase + waveN * 64 + j * 16 + rr;
        float bj = bias[col];
#pragma unroll
        for (int i = 0; i < 4; i++) {
            int row0 = mBase + waveM * 64 + i * 16 + rbase;
#pragma unroll
            for (int r = 0; r < 4; r++) {
                float v = acc[i][j][r] + bj;
                if (RELU) v = fmaxf(v, 0.f);
                if (OBF16)
                    ((unsigned short*)Cout)[(size_t)(row0 + r) * N + col] = f2bf(v);
                else
                    ((float*)Cout)[(size_t)(row0 + r) * N + col] = v;
            }
        }
    }
}

// ======================= MFMA attention ===========================
// One block per (set, head). 256 threads = 4 waves; wave wq owns queries
// [wq*32, wq*32+32). QK: [NVOX][512] bf16 (cols 0-255 Q, 256-511 K).
// V: [NVOX][256] bf16. Output ao: [NVOX][256] bf16.
__global__ __launch_bounds__(256)
void attn_mfma_kernel(const unsigned short* __restrict__ QK,
                      const unsigned short* __restrict__ V,
                      const unsigned char* __restrict__ mask,
                      unsigned short* __restrict__ ao) {
    int s = blockIdx.x, h = blockIdx.y;
    int tid = threadIdx.x;
    int wq = tid >> 6;
    int lane = tid & 63;

    __shared__ alignas(16) unsigned short Ks[128 * 40];   // [key][40] padded (80B rows)
    __shared__ alignas(16) unsigned short Vt[32 * 136];   // [dim][136] padded (272B rows)
    __shared__ alignas(16) unsigned short Plds[4 * 4096]; // per-wave 32x128 bf16, XOR-swizzled
    __shared__ unsigned char msk[SSZ];

    // ---- stage K (natural) + V (transposed) ----
#pragma unroll
    for (int it = 0; it < 2; it++) {
        int idx = tid + it * 256;
        int key = idx >> 2, dimoff = (idx & 3) * 8;
        bf16x8 kv = *(const bf16x8*)(QK + (size_t)(s * SSZ + key) * 512 + 256 + h * HDIM + dimoff);
        *(bf16x8*)(Ks + key * 40 + dimoff) = kv;
        u16x8 vv = *(const u16x8*)(V + (size_t)(s * SSZ + key) * DM + h * HDIM + dimoff);
#pragma unroll
        for (int j = 0; j < 8; j++) Vt[(dimoff + j) * 136 + key] = vv[j];
    }
    if (tid < SSZ) msk[tid] = mask[s * SSZ + tid];
    __syncthreads();

    int rr = lane & 15;
    int kq = (lane >> 4) * 8;
    const f32x4 zero = {0.f, 0.f, 0.f, 0.f};

    // ---- Q fragments straight from global (A-operand layout) ----
    bf16x8 qa[2];
#pragma unroll
    for (int mt = 0; mt < 2; mt++)
        qa[mt] = *(const bf16x8*)(QK + (size_t)(s * SSZ + wq * 32 + mt * 16 + rr) * 512 + h * HDIM + kq);

    // ---- S = Q K^T (32 queries x 128 keys), 16 MFMA ----
    f32x4 S[2][8];
#pragma unroll
    for (int nt = 0; nt < 8; nt++) {
        bf16x8 kb = *(const bf16x8*)(Ks + (nt * 16 + rr) * 40 + kq);
#pragma unroll
        for (int mt = 0; mt < 2; mt++)
            S[mt][nt] = __builtin_amdgcn_mfma_f32_16x16x32_bf16(qa[mt], kb, zero, 0, 0, 0);
    }

    // ---- scale + mask + row max ----
    const float SCALE = 0.17677669529663687f;  // 1/sqrt(32)
    f32x4 rm[2];
#pragma unroll
    for (int mt = 0; mt < 2; mt++) { rm[mt].x = rm[mt].y = rm[mt].z = rm[mt].w = -1e30f; }
#pragma unroll
    for (int nt = 0; nt < 8; nt++) {
        bool mv = msk[nt * 16 + rr] != 0;
#pragma unroll
        for (int mt = 0; mt < 2; mt++) {
#pragma unroll
            for (int r = 0; r < 4; r++) {
                float v = mv ? -1e30f : S[mt][nt][r] * SCALE;
                S[mt][nt][r] = v;
                rm[mt][r] = fmaxf(rm[mt][r], v);
            }
        }
    }
#pragma unroll
    for (int off = 1; off < 16; off <<= 1) {
#pragma unroll
        for (int mt = 0; mt < 2; mt++)
#pragma unroll
            for (int r = 0; r < 4; r++)
                rm[mt][r] = fmaxf(rm[mt][r], __shfl_xor(rm[mt][r], off));
    }

    // ---- exp + row sum; P stays in S regs ----
    f32x4 rs[2];
#pragma unroll
    for (int mt = 0; mt < 2; mt++) { rs[mt] = zero; }
#pragma unroll
    for (int nt = 0; nt < 8; nt++)
#pragma unroll
        for (int mt = 0; mt < 2; mt++)
#pragma unroll
            for (int r = 0; r < 4; r++) {
                float p = __expf(S[mt][nt][r] - rm[mt][r]);
                S[mt][nt][r] = p;
                rs[mt][r] += p;
            }
#pragma unroll
    for (int off = 1; off < 16; off <<= 1) {
#pragma unroll
        for (int mt = 0; mt < 2; mt++)
#pragma unroll
            for (int r = 0; r < 4; r++)
                rs[mt][r] += __shfl_xor(rs[mt][r], off);
    }

    // ---- write P (bf16) to XOR-swizzled LDS strip ----
    char* Pbase = (char*)Plds + wq * 8192;
#pragma unroll
    for (int nt = 0; nt < 8; nt++)
#pragma unroll
        for (int mt = 0; mt < 2; mt++)
#pragma unroll
            for (int r = 0; r < 4; r++) {
                int prow = mt * 16 + (lane >> 4) * 4 + r;
                int col  = nt * 16 + rr;
                unsigned addr = (unsigned)(prow * 256 + col * 2) ^ ((prow & 7) << 4);
                *(unsigned short*)(Pbase + addr) = f2bf(S[mt][nt][r]);
            }
    __syncthreads();

    // ---- O = P V (32 queries x 32 dims), 16 MFMA ----
    f32x4 O[2][2];
#pragma unroll
    for (int mt = 0; mt < 2; mt++)
#pragma unroll
        for (int nd = 0; nd < 2; nd++) O[mt][nd] = zero;
#pragma unroll
    for (int kc = 0; kc < 4; kc++) {
        bf16x8 pa[2];
#pragma unroll
        for (int mt = 0; mt < 2; mt++) {
            int prow = mt * 16 + rr;
            unsigned addr = (unsigned)(prow * 256 + (kc * 32 + kq) * 2) ^ ((prow & 7) << 4);
            pa[mt] = *(const bf16x8*)(Pbase + addr);
        }
#pragma unroll
        for (int nd = 0; nd < 2; nd++) {
            bf16x8 vb = *(const bf16x8*)(Vt + (nd * 16 + rr) * 136 + kc * 32 + kq);
#pragma unroll
            for (int mt = 0; mt < 2; mt++)
                O[mt][nd] = __builtin_amdgcn_mfma_f32_16x16x32_bf16(pa[mt], vb, O[mt][nd], 0, 0, 0);
        }
    }

    // ---- normalize + store bf16 ----
#pragma unroll
    for (int mt = 0; mt < 2; mt++) {
#pragma unroll
        for (int nd = 0; nd < 2; nd++) {
#pragma unroll
            for (int r = 0; r < 4; r++) {
                int row = s * SSZ + wq * 32 + mt * 16 + (lane >> 4) * 4 + r;
                int col = h * HDIM + nd * 16 + rr;
                ao[(size_t)row * DM + col] = f2bf(O[mt][nd][r] / rs[mt][r]);
            }
        }
    }
}

// ======================== LayerNorm helpers =======================
__device__ inline float4 ln4(float4 t, int lane, const float* __restrict__ g,
                             const float* __restrict__ b) {
    float s = t.x + t.y + t.z + t.w;
    float s2 = t.x * t.x + t.y * t.y + t.z * t.z + t.w * t.w;
#pragma unroll
    for (int off = 32; off; off >>= 1) {
        s += __shfl_xor(s, off);
        s2 += __shfl_xor(s2, off);
    }
    float mean = s * (1.0f / 256.0f);
    float var = fmaf(-mean, mean, s2 * (1.0f / 256.0f));
    float rs = rsqrtf(var + 1e-5f);
    float4 g4 = ((const float4*)g)[lane];
    float4 b4 = ((const float4*)b)[lane];
    float4 o;
    o.x = fmaf((t.x - mean) * rs, g4.x, b4.x);
    o.y = fmaf((t.y - mean) * rs, g4.y, b4.y);
    o.z = fmaf((t.z - mean) * rs, g4.z, b4.z);
    o.w = fmaf((t.w - mean) * rs, g4.w, b4.w);
    return o;
}

// x[inds[j]] = LN(prev[inds[j]] + a[j]); a is bf16; dual write f32 + bf16
__global__ __launch_bounds__(256)
void scatter_ln_kernel(const unsigned short* __restrict__ a, const int* __restrict__ inds,
                       const float* __restrict__ prev,
                       const float* __restrict__ g, const float* __restrict__ b,
                       float* __restrict__ x, unsigned short* __restrict__ x_bf) {
    int j = blockIdx.x * 4 + (threadIdx.x >> 6);
    int lane = threadIdx.x & 63;
    int v = inds[j];
    ushort4 av = ((const ushort4*)(a + (size_t)j * DM))[lane];
    float4 pv = ((const float4*)(prev + (size_t)v * DM))[lane];
    float4 t = make_float4(bf2f(av.x) + pv.x, bf2f(av.y) + pv.y,
                           bf2f(av.z) + pv.z, bf2f(av.w) + pv.w);
    float4 o = ln4(t, lane, g, b);
    ((float4*)(x + (size_t)v * DM))[lane] = o;
    ushort4 ob;
    ob.x = f2bf(o.x); ob.y = f2bf(o.y); ob.z = f2bf(o.z); ob.w = f2bf(o.w);
    ((ushort4*)(x_bf + (size_t)v * DM))[lane] = ob;
}

// out[v] = LN( LN(x[v]+y[v], g2,b2) + prev[v], gl,bl )
__global__ __launch_bounds__(256)
void final_ln_kernel(const float* __restrict__ x, const float* __restrict__ y,
                     const float* __restrict__ prev,
                     const float* __restrict__ g2, const float* __restrict__ b2,
                     const float* __restrict__ gl, const float* __restrict__ bl,
                     float* __restrict__ out) {
    int v = blockIdx.x * 4 + (threadIdx.x >> 6);
    int lane = threadIdx.x & 63;
    size_t base = (size_t)v * DM;
    float4 xv = ((const float4*)(x + base))[lane];
    float4 yv = ((const float4*)(y + base))[lane];
    float4 t = make_float4(xv.x + yv.x, xv.y + yv.y, xv.z + yv.z, xv.w + yv.w);
    float4 t2 = ln4(t, lane, g2, b2);
    float4 pv = ((const float4*)(prev + base))[lane];
    float4 u = make_float4(t2.x + pv.x, t2.y + pv.y, t2.z + pv.z, t2.w + pv.w);
    float4 o = ln4(u, lane, gl, bl);
    ((float4*)(out + base))[lane] = o;
}

// ============================= launch =============================
extern "C" void kernel_launch(void* const* d_in, const int* in_sizes, int n_in,
                              void* d_out, int out_size, void* d_ws, size_t ws_size,
                              hipStream_t stream) {
    const float* src       = (const float*)d_in[0];
    const float* pos_embed = (const float*)d_in[1];
    const int*   inds_all  = (const int*)d_in[2];
    const unsigned char* masks_all = (const unsigned char*)d_in[3];
    const float* w_qkv = (const float*)d_in[4];
    const float* b_qkv = (const float*)d_in[5];
    const float* w_out = (const float*)d_in[6];
    const float* b_out = (const float*)d_in[7];
    const float* w_ff1 = (const float*)d_in[8];
    const float* b_ff1 = (const float*)d_in[9];
    const float* w_ff2 = (const float*)d_in[10];
    const float* b_ff2 = (const float*)d_in[11];
    const float* g_n1 = (const float*)d_in[12];
    const float* b_n1 = (const float*)d_in[13];
    const float* g_n2 = (const float*)d_in[14];
    const float* b_n2 = (const float*)d_in[15];
    const float* g_ln = (const float*)d_in[16];
    const float* b_ln = (const float*)d_in[17];
    float* out = (float*)d_out;

    const size_t NVF = (size_t)NVOX * DM;  // 16,777,216
    // ws layout (bf16-centric):
    unsigned short* A = (unsigned short*)d_ws;   // NVF u16: qk_bf -> ao_bf
    unsigned short* B = A + NVF;                 // NVF u16: feat_bf -> x_bf
    unsigned short* C = B + NVF;                 // 2*NVF u16: [Q|K] bf16 -> a_bf -> y(f32)
    unsigned short* D = C + 2 * NVF;             // NVF u16: V bf16
    float* F = (float*)(D + NVF);                // NVF f32: x
    unsigned short* wts = (unsigned short*)(F + NVF);
    const size_t SZ_QKV = (size_t)2 * 3 * DM * DM;
    const size_t SZ_WO  = (size_t)2 * DM * DM;
    const size_t SZ_FF1 = (size_t)2 * DFFN * DM;
    const size_t SZ_FF2 = (size_t)2 * DM * DFFN;
    unsigned short* wqkv_bf = wts;
    unsigned short* wo_bf   = wqkv_bf + SZ_QKV;
    unsigned short* wff1_bf = wo_bf + SZ_WO;
    unsigned short* wff2_bf = wff1_bf + SZ_FF1;
    unsigned short* hbuf    = wff2_bf + SZ_FF2;

    size_t used_bytes = (char*)hbuf - (char*)d_ws;
    long long avail = (long long)ws_size - (long long)used_bytes;
    long long crows = avail / (DFFN * 2);
    if (crows > NVOX) crows = NVOX;
    crows &= ~127LL;
    int chunk = (crows < 128) ? 128 : (int)crows;

    cvt_bf16_kernel<<<512, 256, 0, stream>>>(w_qkv, wqkv_bf, (int)SZ_QKV);
    cvt_bf16_kernel<<<256, 256, 0, stream>>>(w_out, wo_bf, (int)SZ_WO);
    cvt_bf16_kernel<<<1024, 256, 0, stream>>>(w_ff1, wff1_bf, (int)SZ_FF1);
    cvt_bf16_kernel<<<1024, 256, 0, stream>>>(w_ff2, wff2_bf, (int)SZ_FF2);

    for (int i = 0; i < 2; i++) {
        const float* prev = (i == 0) ? src : out;
        const int* inds = inds_all + (size_t)i * 2 * SNUM * SSZ;
        const unsigned char* mask = masks_all + (size_t)i * 2 * SNUM * SSZ;
        const float* pos  = pos_embed + (size_t)i * NVF;
        const unsigned short* wqkv = wqkv_bf + (size_t)i * 3 * DM * DM;
        const unsigned short* wo   = wo_bf + (size_t)i * DM * DM;
        const unsigned short* wff1 = wff1_bf + (size_t)i * DFFN * DM;
        const unsigned short* wff2 = wff2_bf + (size_t)i * DM * DFFN;
        const float* bqkv = b_qkv + (size_t)i * 3 * DM;
        const float* bo   = b_out + (size_t)i * DM;
        const float* bff1 = b_ff1 + (size_t)i * DFFN;
        const float* bff2 = b_ff2 + (size_t)i * DM;

        // gather: A = bf16(src+pos), B = bf16(src)
        gather_kernel<<<NVOX / 4, 256, 0, stream>>>(prev, pos, inds, A, B);

        // [Q|K] = qk @ [Wq;Wk]^T -> C (bf16, NVOX x 512)
        gemm_mfma<false, true><<<dim3(NVOX / 128, 512 / 128), 256, 0, stream>>>(
            A, wqkv, bqkv, C, NVOX, 512, DM);
        // V = feat @ Wv^T -> D (bf16)
        gemm_mfma<false, true><<<dim3(NVOX / 128, DM / 128), 256, 0, stream>>>(
            B, wqkv + (size_t)512 * DM, bqkv + 512, D, NVOX, DM, DM);

        // attention -> ao (bf16, reuse A)
        attn_mfma_kernel<<<dim3(SNUM, NH), 256, 0, stream>>>(C, D, mask, A);

        // a = ao @ Wo^T + bo -> C (bf16, NVOX x 256; C's [Q|K] consumed)
        gemm_mfma<false, true><<<dim3(NVOX / 128, DM / 128), 256, 0, stream>>>(
            A, wo, bo, C, NVOX, DM, DM);

        // x = LN(prev + scatter(a)) -> F (f32) + B (bf16)
        scatter_ln_kernel<<<NVOX / 4, 256, 0, stream>>>(
            C, inds, prev, g_n1 + i * DM, b_n1 + i * DM, F, B);

        // FFN row-chunked: h = relu(x_bf@W1^T+b1) bf16; y = h@W2^T+b2 -> C (f32)
        float* y = (float*)C;
        for (int r0 = 0; r0 < NVOX; r0 += chunk) {
            int rows = (NVOX - r0 < chunk) ? (NVOX - r0) : chunk;
            gemm_mfma<true, true><<<dim3(rows / 128, DFFN / 128), 256, 0, stream>>>(
                B + (size_t)r0 * DM, wff1, bff1, hbuf, rows, DFFN, DM);
            gemm_mfma<false, false><<<dim3(rows / 128, DM / 128), 256, 0, stream>>>(
                hbuf, wff2, bff2, y + (size_t)r0 * DM, rows, DM, DFFN);
        }

        // out = LN( LN(x+y) + prev )
        final_ln_kernel<<<NVOX / 4, 256, 0, stream>>>(
            F, y, prev, g_n2 + i * DM, b_n2 + i * DM,
            g_ln + i * DM, b_ln + i * DM, out);
    }
}

// Round 4
// 1162.873 us; speedup vs baseline: 4.3205x; 1.0415x over previous
//
#include <hip/hip_runtime.h>
#include <math.h>

#define NVOX 65536
#define DM 256
#define NH 8
#define HDIM 32
#define DFFN 2048
#define SSZ 128
#define SNUM 512

#define AS1 __attribute__((address_space(1)))
#define AS3 __attribute__((address_space(3)))

typedef __attribute__((ext_vector_type(8))) __bf16 bf16x8;
typedef __attribute__((ext_vector_type(8))) unsigned short u16x8;
typedef __attribute__((ext_vector_type(4))) float f32x4;

__device__ __forceinline__ unsigned short f2bf(float f) {
    unsigned int u = __float_as_uint(f);
    u += 0x7fffu + ((u >> 16) & 1u);
    return (unsigned short)(u >> 16);
}
__device__ __forceinline__ float bf2f(unsigned short u) {
    return __uint_as_float(((unsigned int)u) << 16);
}

// ===================== weight fp32 -> bf16 ========================
__global__ __launch_bounds__(256)
void cvt_bf16_kernel(const float* __restrict__ in, unsigned short* __restrict__ out, int n) {
    int i = blockIdx.x * 256 + threadIdx.x;
    int stride = gridDim.x * 256;
    for (; i < n; i += stride) out[i] = f2bf(in[i]);
}

// ============================= gather =============================
__global__ __launch_bounds__(256)
void gather_kernel(const float* __restrict__ src, const float* __restrict__ pos,
                   const int* __restrict__ inds,
                   unsigned short* __restrict__ qk, unsigned short* __restrict__ feat) {
    int j = blockIdx.x * 4 + (threadIdx.x >> 6);
    int lane = threadIdx.x & 63;
    int v = inds[j];
    float4 a = ((const float4*)(src + (size_t)v * DM))[lane];
    float4 p = ((const float4*)(pos + (size_t)v * DM))[lane];
    ushort4 qo, fo;
    qo.x = f2bf(a.x + p.x); qo.y = f2bf(a.y + p.y);
    qo.z = f2bf(a.z + p.z); qo.w = f2bf(a.w + p.w);
    fo.x = f2bf(a.x); fo.y = f2bf(a.y); fo.z = f2bf(a.z); fo.w = f2bf(a.w);
    ((ushort4*)(qk   + (size_t)j * DM))[lane] = qo;
    ((ushort4*)(feat + (size_t)j * DM))[lane] = fo;
}

// ========================= bf16 MFMA GEMM =========================
// C[M,N] = A[M,K](bf16) @ W[N,K](bf16)^T + bias[N](f32); opt ReLU; out f32/bf16.
// 128x128 tile, BK=32, 4 waves (2x2), 16x16x32 MFMA.
// v2: double-buffered prefetch K-loop (1 barrier/step) + LDS-staged
//     vectorized epilogue (full-line stores, no RMW).
template<bool RELU, bool OBF16>
__global__ __launch_bounds__(256)
void gemm_mfma(const unsigned short* __restrict__ A, const unsigned short* __restrict__ W,
               const float* __restrict__ bias, void* __restrict__ Cout,
               int M, int N, int K) {
    // LDS: dbuf As[2][4096] u16 (16KB) + Bs[2][4096] u16 (16KB) = 32KB,
    // epilogue f32 strip (32x132 = 16.9KB) aliased on top after K-loop.
    __shared__ alignas(16) char smem[32768];
    unsigned short* As = (unsigned short*)smem;           // buf b at b*4096
    unsigned short* Bs = (unsigned short*)(smem + 16384); // buf b at b*4096
    float* ebuf = (float*)smem;
    const int ESTRIDE = 132;

    int tid = threadIdx.x;
    int wave = tid >> 6, lane = tid & 63;
    int waveM = wave >> 1, waveN = wave & 1;
    int mBase = blockIdx.x * 128, nBase = blockIdx.y * 128;

    f32x4 acc[4][4];
    const f32x4 zero = {0.f, 0.f, 0.f, 0.f};
#pragma unroll
    for (int i = 0; i < 4; i++)
#pragma unroll
        for (int j = 0; j < 4; j++) acc[i][j] = zero;

    int lrow = lane >> 2;        // 0..15 row within 16-row stripe
    int lk   = (lane & 3) * 8;   // k-elem offset (16B per lane)
    int kh   = (lane >> 4) * 8;  // fragment k-offset
    int rr   = lane & 15;        // fragment row/col
    int rbase = (lane >> 4) * 4;

    auto stage = [&](int b, int k0) {
#pragma unroll
        for (int u = 0; u < 2; ++u) {
            int w2 = wave * 2 + u;  // stripe 0..7 (16 rows each)
            const unsigned short* ga = A + (size_t)(mBase + w2 * 16 + lrow) * K + k0 + lk;
            __builtin_amdgcn_global_load_lds((const AS1 void*)ga,
                (AS3 void*)(As + b * 4096 + w2 * 512), 16, 0, 0);
            const unsigned short* gb = W + (size_t)(nBase + w2 * 16 + lrow) * K + k0 + lk;
            __builtin_amdgcn_global_load_lds((const AS1 void*)gb,
                (AS3 void*)(Bs + b * 4096 + w2 * 512), 16, 0, 0);
        }
    };

    int nt = K >> 5;
    // prologue: stage tile 0, drain, barrier
    stage(0, 0);
    __syncthreads();

    int cur = 0;
    for (int t = 0; t < nt; ++t) {
        // issue next-tile loads FIRST so their latency hides under MFMA
        if (t + 1 < nt) stage(cur ^ 1, (t + 1) << 5);

        bf16x8 af[4], bfr[4];
#pragma unroll
        for (int i = 0; i < 4; i++)
            af[i] = *(const bf16x8*)(As + cur * 4096 + (waveM * 64 + i * 16 + rr) * 32 + kh);
#pragma unroll
        for (int j = 0; j < 4; j++)
            bfr[j] = *(const bf16x8*)(Bs + cur * 4096 + (waveN * 64 + j * 16 + rr) * 32 + kh);
#pragma unroll
        for (int i = 0; i < 4; i++)
#pragma unroll
            for (int j = 0; j < 4; j++)
                acc[i][j] = __builtin_amdgcn_mfma_f32_16x16x32_bf16(af[i], bfr[j], acc[i][j], 0, 0, 0);

        if (t + 1 < nt) {
            __syncthreads();  // compiler-emitted vmcnt(0) completes prefetch
            cur ^= 1;
        }
    }

    // ---- epilogue: 4 passes of 32 rows via LDS, vectorized stores ----
    float bn[4];
#pragma unroll
    for (int j = 0; j < 4; j++)
        bn[j] = bias[nBase + waveN * 64 + j * 16 + rr];

    int erow = tid >> 3;              // 0..31
    int ecol = (tid & 7) * 16;        // 0..112
#pragma unroll
    for (int ph = 0; ph < 4; ++ph) {
        __syncthreads();  // pass 0: also protects LDS reuse after K-loop
        if (waveM == (ph >> 1)) {
#pragma unroll
            for (int ii = 0; ii < 2; ++ii) {
                int i = (ph & 1) * 2 + ii;
#pragma unroll
                for (int j = 0; j < 4; ++j) {
                    int lcol = waveN * 64 + j * 16 + rr;
#pragma unroll
                    for (int r = 0; r < 4; ++r) {
                        float v = acc[i][j][r] + bn[j];
                        if (RELU) v = fmaxf(v, 0.f);
                        ebuf[(ii * 16 + rbase + r) * ESTRIDE + lcol] = v;
                    }
                }
            }
        }
        __syncthreads();
        int grow = mBase + ph * 32 + erow;
        if (OBF16) {
            u16x8 o0, o1;
#pragma unroll
            for (int g = 0; g < 8; ++g) {
                o0[g] = f2bf(ebuf[erow * ESTRIDE + ecol + g]);
                o1[g] = f2bf(ebuf[erow * ESTRIDE + ecol + 8 + g]);
            }
            u16x8* dst = (u16x8*)((unsigned short*)Cout + (size_t)grow * N + nBase + ecol);
            dst[0] = o0;
            dst[1] = o1;
        } else {
            float* dst = (float*)Cout + (size_t)grow * N + nBase + ecol;
#pragma unroll
            for (int g = 0; g < 4; ++g)
                *(float4*)(dst + g * 4) = *(float4*)(ebuf + erow * ESTRIDE + ecol + g * 4);
        }
    }
}

// ======================= MFMA attention ===========================
// One block per (set, head). 256 threads = 4 waves; wave wq owns queries
// [wq*32, wq*32+32). QK: [NVOX][512] bf16 (cols 0-255 Q, 256-511 K).
__global__ __launch_bounds__(256)
void attn_mfma_kernel(const unsigned short* __restrict__ QK,
                      const unsigned short* __restrict__ V,
                      const unsigned char* __restrict__ mask,
                      unsigned short* __restrict__ ao) {
    int s = blockIdx.x, h = blockIdx.y;
    int tid = threadIdx.x;
    int wq = tid >> 6;
    int lane = tid & 63;

    __shared__ alignas(16) unsigned short Ks[128 * 40];
    __shared__ alignas(16) unsigned short Vt[32 * 136];
    __shared__ alignas(16) unsigned short Plds[4 * 4096];
    __shared__ unsigned char msk[SSZ];

#pragma unroll
    for (int it = 0; it < 2; it++) {
        int idx = tid + it * 256;
        int key = idx >> 2, dimoff = (idx & 3) * 8;
        bf16x8 kv = *(const bf16x8*)(QK + (size_t)(s * SSZ + key) * 512 + 256 + h * HDIM + dimoff);
        *(bf16x8*)(Ks + key * 40 + dimoff) = kv;
        u16x8 vv = *(const u16x8*)(V + (size_t)(s * SSZ + key) * DM + h * HDIM + dimoff);
#pragma unroll
        for (int j = 0; j < 8; j++) Vt[(dimoff + j) * 136 + key] = vv[j];
    }
    if (tid < SSZ) msk[tid] = mask[s * SSZ + tid];
    __syncthreads();

    int rr = lane & 15;
    int kq = (lane >> 4) * 8;
    const f32x4 zero = {0.f, 0.f, 0.f, 0.f};

    bf16x8 qa[2];
#pragma unroll
    for (int mt = 0; mt < 2; mt++)
        qa[mt] = *(const bf16x8*)(QK + (size_t)(s * SSZ + wq * 32 + mt * 16 + rr) * 512 + h * HDIM + kq);

    f32x4 S[2][8];
#pragma unroll
    for (int nt = 0; nt < 8; nt++) {
        bf16x8 kb = *(const bf16x8*)(Ks + (nt * 16 + rr) * 40 + kq);
#pragma unroll
        for (int mt = 0; mt < 2; mt++)
            S[mt][nt] = __builtin_amdgcn_mfma_f32_16x16x32_bf16(qa[mt], kb, zero, 0, 0, 0);
    }

    const float SCALE = 0.17677669529663687f;
    f32x4 rm[2];
#pragma unroll
    for (int mt = 0; mt < 2; mt++) { rm[mt].x = rm[mt].y = rm[mt].z = rm[mt].w = -1e30f; }
#pragma unroll
    for (int nt = 0; nt < 8; nt++) {
        bool mv = msk[nt * 16 + rr] != 0;
#pragma unroll
        for (int mt = 0; mt < 2; mt++) {
#pragma unroll
            for (int r = 0; r < 4; r++) {
                float v = mv ? -1e30f : S[mt][nt][r] * SCALE;
                S[mt][nt][r] = v;
                rm[mt][r] = fmaxf(rm[mt][r], v);
            }
        }
    }
#pragma unroll
    for (int off = 1; off < 16; off <<= 1) {
#pragma unroll
        for (int mt = 0; mt < 2; mt++)
#pragma unroll
            for (int r = 0; r < 4; r++)
                rm[mt][r] = fmaxf(rm[mt][r], __shfl_xor(rm[mt][r], off));
    }

    f32x4 rs[2];
#pragma unroll
    for (int mt = 0; mt < 2; mt++) { rs[mt] = zero; }
#pragma unroll
    for (int nt = 0; nt < 8; nt++)
#pragma unroll
        for (int mt = 0; mt < 2; mt++)
#pragma unroll
            for (int r = 0; r < 4; r++) {
                float p = __expf(S[mt][nt][r] - rm[mt][r]);
                S[mt][nt][r] = p;
                rs[mt][r] += p;
            }
#pragma unroll
    for (int off = 1; off < 16; off <<= 1) {
#pragma unroll
        for (int mt = 0; mt < 2; mt++)
#pragma unroll
            for (int r = 0; r < 4; r++)
                rs[mt][r] += __shfl_xor(rs[mt][r], off);
    }

    char* Pbase = (char*)Plds + wq * 8192;
#pragma unroll
    for (int nt = 0; nt < 8; nt++)
#pragma unroll
        for (int mt = 0; mt < 2; mt++)
#pragma unroll
            for (int r = 0; r < 4; r++) {
                int prow = mt * 16 + (lane >> 4) * 4 + r;
                int col  = nt * 16 + rr;
                unsigned addr = (unsigned)(prow * 256 + col * 2) ^ ((prow & 7) << 4);
                *(unsigned short*)(Pbase + addr) = f2bf(S[mt][nt][r]);
            }
    __syncthreads();

    f32x4 O[2][2];
#pragma unroll
    for (int mt = 0; mt < 2; mt++)
#pragma unroll
        for (int nd = 0; nd < 2; nd++) O[mt][nd] = zero;
#pragma unroll
    for (int kc = 0; kc < 4; kc++) {
        bf16x8 pa[2];
#pragma unroll
        for (int mt = 0; mt < 2; mt++) {
            int prow = mt * 16 + rr;
            unsigned addr = (unsigned)(prow * 256 + (kc * 32 + kq) * 2) ^ ((prow & 7) << 4);
            pa[mt] = *(const bf16x8*)(Pbase + addr);
        }
#pragma unroll
        for (int nd = 0; nd < 2; nd++) {
            bf16x8 vb = *(const bf16x8*)(Vt + (nd * 16 + rr) * 136 + kc * 32 + kq);
#pragma unroll
            for (int mt = 0; mt < 2; mt++)
                O[mt][nd] = __builtin_amdgcn_mfma_f32_16x16x32_bf16(pa[mt], vb, O[mt][nd], 0, 0, 0);
        }
    }

#pragma unroll
    for (int mt = 0; mt < 2; mt++) {
#pragma unroll
        for (int nd = 0; nd < 2; nd++) {
#pragma unroll
            for (int r = 0; r < 4; r++) {
                int row = s * SSZ + wq * 32 + mt * 16 + (lane >> 4) * 4 + r;
                int col = h * HDIM + nd * 16 + rr;
                ao[(size_t)row * DM + col] = f2bf(O[mt][nd][r] / rs[mt][r]);
            }
        }
    }
}

// ======================== LayerNorm helpers =======================
__device__ inline float4 ln4(float4 t, int lane, const float* __restrict__ g,
                             const float* __restrict__ b) {
    float s = t.x + t.y + t.z + t.w;
    float s2 = t.x * t.x + t.y * t.y + t.z * t.z + t.w * t.w;
#pragma unroll
    for (int off = 32; off; off >>= 1) {
        s += __shfl_xor(s, off);
        s2 += __shfl_xor(s2, off);
    }
    float mean = s * (1.0f / 256.0f);
    float var = fmaf(-mean, mean, s2 * (1.0f / 256.0f));
    float rs = rsqrtf(var + 1e-5f);
    float4 g4 = ((const float4*)g)[lane];
    float4 b4 = ((const float4*)b)[lane];
    float4 o;
    o.x = fmaf((t.x - mean) * rs, g4.x, b4.x);
    o.y = fmaf((t.y - mean) * rs, g4.y, b4.y);
    o.z = fmaf((t.z - mean) * rs, g4.z, b4.z);
    o.w = fmaf((t.w - mean) * rs, g4.w, b4.w);
    return o;
}

// x[inds[j]] = LN(prev[inds[j]] + a[j]); a is bf16; dual write f32 + bf16
__global__ __launch_bounds__(256)
void scatter_ln_kernel(const unsigned short* __restrict__ a, const int* __restrict__ inds,
                       const float* __restrict__ prev,
                       const float* __restrict__ g, const float* __restrict__ b,
                       float* __restrict__ x, unsigned short* __restrict__ x_bf) {
    int j = blockIdx.x * 4 + (threadIdx.x >> 6);
    int lane = threadIdx.x & 63;
    int v = inds[j];
    ushort4 av = ((const ushort4*)(a + (size_t)j * DM))[lane];
    float4 pv = ((const float4*)(prev + (size_t)v * DM))[lane];
    float4 t = make_float4(bf2f(av.x) + pv.x, bf2f(av.y) + pv.y,
                           bf2f(av.z) + pv.z, bf2f(av.w) + pv.w);
    float4 o = ln4(t, lane, g, b);
    ((float4*)(x + (size_t)v * DM))[lane] = o;
    ushort4 ob;
    ob.x = f2bf(o.x); ob.y = f2bf(o.y); ob.z = f2bf(o.z); ob.w = f2bf(o.w);
    ((ushort4*)(x_bf + (size_t)v * DM))[lane] = ob;
}

// out[v] = LN( LN(x[v]+y[v], g2,b2) + prev[v], gl,bl )
__global__ __launch_bounds__(256)
void final_ln_kernel(const float* __restrict__ x, const float* __restrict__ y,
                     const float* __restrict__ prev,
                     const float* __restrict__ g2, const float* __restrict__ b2,
                     const float* __restrict__ gl, const float* __restrict__ bl,
                     float* __restrict__ out) {
    int v = blockIdx.x * 4 + (threadIdx.x >> 6);
    int lane = threadIdx.x & 63;
    size_t base = (size_t)v * DM;
    float4 xv = ((const float4*)(x + base))[lane];
    float4 yv = ((const float4*)(y + base))[lane];
    float4 t = make_float4(xv.x + yv.x, xv.y + yv.y, xv.z + yv.z, xv.w + yv.w);
    float4 t2 = ln4(t, lane, g2, b2);
    float4 pv = ((const float4*)(prev + base))[lane];
    float4 u = make_float4(t2.x + pv.x, t2.y + pv.y, t2.z + pv.z, t2.w + pv.w);
    float4 o = ln4(u, lane, gl, bl);
    ((float4*)(out + base))[lane] = o;
}

// ============================= launch =============================
extern "C" void kernel_launch(void* const* d_in, const int* in_sizes, int n_in,
                              void* d_out, int out_size, void* d_ws, size_t ws_size,
                              hipStream_t stream) {
    const float* src       = (const float*)d_in[0];
    const float* pos_embed = (const float*)d_in[1];
    const int*   inds_all  = (const int*)d_in[2];
    const unsigned char* masks_all = (const unsigned char*)d_in[3];
    const float* w_qkv = (const float*)d_in[4];
    const float* b_qkv = (const float*)d_in[5];
    const float* w_out = (const float*)d_in[6];
    const float* b_out = (const float*)d_in[7];
    const float* w_ff1 = (const float*)d_in[8];
    const float* b_ff1 = (const float*)d_in[9];
    const float* w_ff2 = (const float*)d_in[10];
    const float* b_ff2 = (const float*)d_in[11];
    const float* g_n1 = (const float*)d_in[12];
    const float* b_n1 = (const float*)d_in[13];
    const float* g_n2 = (const float*)d_in[14];
    const float* b_n2 = (const float*)d_in[15];
    const float* g_ln = (const float*)d_in[16];
    const float* b_ln = (const float*)d_in[17];
    float* out = (float*)d_out;

    const size_t NVF = (size_t)NVOX * DM;  // 16,777,216
    unsigned short* A = (unsigned short*)d_ws;   // NVF u16: qk_bf -> ao_bf
    unsigned short* B = A + NVF;                 // NVF u16: feat_bf -> x_bf
    unsigned short* C = B + NVF;                 // 2*NVF u16: [Q|K] -> a_bf -> y(f32)
    unsigned short* D = C + 2 * NVF;             // NVF u16: V bf16
    float* F = (float*)(D + NVF);                // NVF f32: x
    unsigned short* wts = (unsigned short*)(F + NVF);
    const size_t SZ_QKV = (size_t)2 * 3 * DM * DM;
    const size_t SZ_WO  = (size_t)2 * DM * DM;
    const size_t SZ_FF1 = (size_t)2 * DFFN * DM;
    const size_t SZ_FF2 = (size_t)2 * DM * DFFN;
    unsigned short* wqkv_bf = wts;
    unsigned short* wo_bf   = wqkv_bf + SZ_QKV;
    unsigned short* wff1_bf = wo_bf + SZ_WO;
    unsigned short* wff2_bf = wff1_bf + SZ_FF1;
    unsigned short* hbuf    = wff2_bf + SZ_FF2;

    size_t used_bytes = (char*)hbuf - (char*)d_ws;
    long long avail = (long long)ws_size - (long long)used_bytes;
    long long crows = avail / (DFFN * 2);
    if (crows > NVOX) crows = NVOX;
    crows &= ~127LL;
    int chunk = (crows < 128) ? 128 : (int)crows;

    cvt_bf16_kernel<<<512, 256, 0, stream>>>(w_qkv, wqkv_bf, (int)SZ_QKV);
    cvt_bf16_kernel<<<256, 256, 0, stream>>>(w_out, wo_bf, (int)SZ_WO);
    cvt_bf16_kernel<<<1024, 256, 0, stream>>>(w_ff1, wff1_bf, (int)SZ_FF1);
    cvt_bf16_kernel<<<1024, 256, 0, stream>>>(w_ff2, wff2_bf, (int)SZ_FF2);

    for (int i = 0; i < 2; i++) {
        const float* prev = (i == 0) ? src : out;
        const int* inds = inds_all + (size_t)i * 2 * SNUM * SSZ;
        const unsigned char* mask = masks_all + (size_t)i * 2 * SNUM * SSZ;
        const float* pos  = pos_embed + (size_t)i * NVF;
        const unsigned short* wqkv = wqkv_bf + (size_t)i * 3 * DM * DM;
        const unsigned short* wo   = wo_bf + (size_t)i * DM * DM;
        const unsigned short* wff1 = wff1_bf + (size_t)i * DFFN * DM;
        const unsigned short* wff2 = wff2_bf + (size_t)i * DM * DFFN;
        const float* bqkv = b_qkv + (size_t)i * 3 * DM;
        const float* bo   = b_out + (size_t)i * DM;
        const float* bff1 = b_ff1 + (size_t)i * DFFN;
        const float* bff2 = b_ff2 + (size_t)i * DM;

        gather_kernel<<<NVOX / 4, 256, 0, stream>>>(prev, pos, inds, A, B);

        gemm_mfma<false, true><<<dim3(NVOX / 128, 512 / 128), 256, 0, stream>>>(
            A, wqkv, bqkv, C, NVOX, 512, DM);
        gemm_mfma<false, true><<<dim3(NVOX / 128, DM / 128), 256, 0, stream>>>(
            B, wqkv + (size_t)512 * DM, bqkv + 512, D, NVOX, DM, DM);

        attn_mfma_kernel<<<dim3(SNUM, NH), 256, 0, stream>>>(C, D, mask, A);

        gemm_mfma<false, true><<<dim3(NVOX / 128, DM / 128), 256, 0, stream>>>(
            A, wo, bo, C, NVOX, DM, DM);

        scatter_ln_kernel<<<NVOX / 4, 256, 0, stream>>>(
            C, inds, prev, g_n1 + i * DM, b_n1 + i * DM, F, B);

        float* y = (float*)C;
        for (int r0 = 0; r0 < NVOX; r0 += chunk) {
            int rows = (NVOX - r0 < chunk) ? (NVOX - r0) : chunk;
            gemm_mfma<true, true><<<dim3(rows / 128, DFFN / 128), 256, 0, stream>>>(
                B + (size_t)r0 * DM, wff1, bff1, hbuf, rows, DFFN, DM);
            gemm_mfma<false, false><<<dim3(rows / 128, DM / 128), 256, 0, stream>>>(
                hbuf, wff2, bff2, y + (size_t)r0 * DM, rows, DM, DFFN);
        }

        final_ln_kernel<<<NVOX / 4, 256, 0, stream>>>(
            F, y, prev, g_n2 + i * DM, b_n2 + i * DM,
            g_ln + i * DM, b_ln + i * DM, out);
    }
}